// Round 5
// baseline (395.572 us; speedup 1.0000x reference)
//
#include <hip/hip_runtime.h>
#include <hip/hip_bf16.h>
#include <math.h>

// Problem constants
#define B_    32
#define FIN   16
#define LIN   8192
#define LAT   64
#define L1V   8190      // length after k=3 valid conv
#define PN    200
#define PLEN  16
#define LOV   8175      // L1V - 16 + 1
#define NCLS  10
#define EPSV  1e-4f
#define MD0   320       // f32 offset of min_distances in d_out
#define CHK   256       // positions per block
#define WIN   272       // window slots (CHK + 16)
#define FST   68        // fwin row stride in u16 (136 B: 2-way bank aliasing = free)
#define NPT   7         // proto tiles of 32 (200 padded to 224)
#define NFRAG (NPT * 16 * 4 * 64)   // 28672 pre-packed B-fragments

typedef unsigned short u16;
typedef unsigned int   u32;
typedef short s16x8 __attribute__((ext_vector_type(8)));   // 8 bf16 (4 VGPRs)
typedef float f32x16 __attribute__((ext_vector_type(16))); // 32x32 MFMA accumulator

union FragU { uint2 u2[2]; s16x8 v; };

__device__ __forceinline__ u16 vf2b(float f) {
    union { float f; u32 u; } v; v.f = f;
    u32 u = v.u;
    return (u16)((u + 0x7fffu + ((u >> 16) & 1u)) >> 16);   // RNE
}

// K0: wsm = FLT_MAX bits; p2g = ||proto||^2; waT = wa transposed [c][o];
//     pk = protos pre-packed as per-lane MFMA B-fragments:
//     frag f = ((p7*16 + tap)*4 + cs)*64 + lane holds 8 bf16:
//     proto (p7*32 + (lane&31)), channels cs*16 + (lane>>5)*8 + j, tap.
__global__ void k_init(const float* __restrict__ pt, const float* __restrict__ wa,
                       u32* __restrict__ wsm, float* __restrict__ p2g,
                       float* __restrict__ waT, u16* __restrict__ pk) {
    const int tid = blockIdx.x * 256 + threadIdx.x;
    const int N   = gridDim.x * 256;

    for (int j = tid; j < B_ * PN; j += N) wsm[j] = 0x7f7fffffu;

    for (int j = tid; j < LAT * LAT; j += N)
        waT[j] = wa[(j & 63) * LAT + (j >> 6)];

    for (int p = tid; p < 224; p += N) {
        float s = 0.f;
        if (p < PN) {
            const float4* pr = (const float4*)(pt + (size_t)p * (LAT * PLEN));
            #pragma unroll 4
            for (int j = 0; j < 256; ++j) {
                float4 v = pr[j];
                s += v.x * v.x + v.y * v.y + v.z * v.z + v.w * v.w;
            }
        }
        p2g[p] = s;
    }

    for (int f = tid; f < NFRAG; f += N) {
        const int lane = f & 63;
        const int cs   = (f >> 6) & 3;
        const int tap  = (f >> 8) & 15;
        const int p7   = f >> 12;
        const int gp   = p7 * 32 + (lane & 31);
        const int chb  = cs * 16 + (lane >> 5) * 8;
        s16x8 v;
        if (gp < PN) {
            const float* src = pt + (size_t)gp * (LAT * PLEN) + (size_t)chb * PLEN + tap;
            #pragma unroll
            for (int j = 0; j < 8; ++j) v[j] = (short)vf2b(src[j * PLEN]);
        } else {
            #pragma unroll
            for (int j = 0; j < 8; ++j) v[j] = 0;
        }
        *(s16x8*)(pk + (size_t)f * 8) = v;
    }
}

// Fused encoder+addon for one position -> fwin POSITION-MAJOR bf16 [slot][64ch] + gwin f32.
__device__ __forceinline__ void enc_pos(int pos, int slot,
                                        const float* __restrict__ xb,
                                        const float* __restrict__ we,
                                        const float* __restrict__ waT,
                                        u32* __restrict__ fw32,
                                        float* __restrict__ gwin) {
    float acc[LAT];
    #pragma unroll
    for (int o = 0; o < LAT; ++o) acc[o] = 0.f;
    if (pos < L1V) {
        float xw[FIN * 3];
        #pragma unroll
        for (int c2 = 0; c2 < FIN; ++c2) {
            xw[c2 * 3 + 0] = xb[(size_t)c2 * LIN + pos + 0];
            xw[c2 * 3 + 1] = xb[(size_t)c2 * LIN + pos + 1];
            xw[c2 * 3 + 2] = xb[(size_t)c2 * LIN + pos + 2];
        }
        #pragma unroll 1
        for (int c = 0; c < LAT; ++c) {
            const float* w = we + c * 48;        // uniform -> s_loads
            float s0 = 0.f, s1 = 0.f, s2 = 0.f, s3 = 0.f;
            #pragma unroll
            for (int q = 0; q < 12; ++q) {
                s0 += xw[q]      * w[q];
                s1 += xw[q + 12] * w[q + 12];
                s2 += xw[q + 24] * w[q + 24];
                s3 += xw[q + 36] * w[q + 36];
            }
            float f1 = fmaxf((s0 + s1) + (s2 + s3), 0.f);
            const float* wc = waT + c * LAT;     // uniform, contiguous
            #pragma unroll
            for (int o = 0; o < LAT; ++o)
                acc[o] += f1 * wc[o];
        }
    }
    float gs = 0.f;
    #pragma unroll
    for (int o2 = 0; o2 < 32; ++o2) {
        float r0 = fmaxf(acc[2 * o2], 0.f);
        float r1 = fmaxf(acc[2 * o2 + 1], 0.f);
        fw32[slot * (FST / 2) + o2] = ((u32)vf2b(r1) << 16) | (u32)vf2b(r0);
        gs += r0 * r0 + r1 * r1;                 // s stays f32-exact
    }
    gwin[slot] = gs;
}

// Issue the staging load for round g (chunk = this wave's 1KB) into buffer buf.
// Round g = (tap = g>>1, cs-pair = g&1); chunk c == wv (wv < 2*NT).
template<int NT>
__device__ __forceinline__ void stage_rd(int p7b, int g, int buf,
                                         const u16* __restrict__ pk,
                                         u16* __restrict__ ldsB,
                                         int wv, int lane) {
    if (wv < 2 * NT) {
        const int tap = g >> 1, csp = g & 1;
        const int n = wv >> 1, csl = wv & 1;
        const int cs = csp * 2 + csl;
        const u16* gsrc = pk + ((size_t)(((p7b + n) * 16 + tap) * 4 + cs) * 64 + lane) * 8;
        u16* ldst = ldsB + (size_t)(buf * 4 + wv) * 512;   // wave-uniform; HW adds lane*16
        __builtin_amdgcn_global_load_lds(
            (const __attribute__((address_space(1))) void*)gsrc,
            (__attribute__((address_space(3))) void*)ldst, 16, 0, 0);
    }
}

// One pass over NT proto-tiles, accumulators AGPR-resident.
// B deduped to once per BLOCK via LDS staging (R1/R3's 448 identical 1KB loads/wave
// through the L1 fill path ~= the whole 190us GEMM phase). R4's failure was schedule:
// prefetch depth 1 = ~64cy cover vs ~300cy L2 latency. Here: triple buffer, prefetch
// issued 2 ROUNDS ahead (~800cy cover), counted vmcnt(1) (never 0 mid-loop, T4),
// one barrier per round, setprio around the MFMA cluster (T5).
// Round protocol (safety): reads of buf (g-1)%3 all precede barrier(g); stage(g+2)
// writes buf (g+2)%3 == (g-1)%3 and is issued after barrier(g). vmcnt counts retire
// oldest-first (m135), so pass-end atomics under vmcnt(1) are safe.
template<int NT>
__device__ __forceinline__ void dist_pass(int p7b,
                                          const u16* __restrict__ pk,
                                          const u16* __restrict__ fwin,
                                          u16* __restrict__ ldsB,
                                          const float* __restrict__ sarr,
                                          const float* __restrict__ p2g,
                                          u32* __restrict__ wsm,
                                          int b, int wv, int lane) {
    const int m    = lane & 31;
    const int half = lane >> 5;
    const int koff = half * 8;

    f32x16 acc[NT][2];
    #pragma unroll
    for (int n = 0; n < NT; ++n)
        #pragma unroll
        for (int i = 0; i < 16; ++i) { acc[n][0][i] = 0.f; acc[n][1][i] = 0.f; }

    __builtin_amdgcn_s_barrier();        // prior pass/phase reads of ldsB complete
    stage_rd<NT>(p7b, 0, 0, pk, ldsB, wv, lane);
    stage_rd<NT>(p7b, 1, 1, pk, ldsB, wv, lane);

    int buf = 0;
    #pragma unroll 1
    for (int g = 0; g < 32; ++g) {
        if (g < 31) asm volatile("s_waitcnt vmcnt(1)" ::: "memory");   // stage(g) landed
        else        asm volatile("s_waitcnt vmcnt(0)" ::: "memory");   // final round drain
        __builtin_amdgcn_s_barrier();    // stage(g) visible to all; reads(g-1) done by all
        __builtin_amdgcn_sched_barrier(0);
        if (g < 30) {
            int nb = buf + 2; if (nb >= 3) nb -= 3;
            stage_rd<NT>(p7b, g + 2, nb, pk, ldsB, wv, lane);
        }

        const int tap = g >> 1, csp = g & 1;
        FragU a[2][2], bf[2][NT];
        #pragma unroll
        for (int csl = 0; csl < 2; ++csl) {
            const int co = (csp * 2 + csl) * 16 + koff;
            const u16* ap = &fwin[(wv * 64 + m + tap) * FST + co];
            a[csl][0].u2[0] = *(const uint2*)ap;
            a[csl][0].u2[1] = *(const uint2*)(ap + 4);
            const u16* aq = ap + 32 * FST;
            a[csl][1].u2[0] = *(const uint2*)aq;
            a[csl][1].u2[1] = *(const uint2*)(aq + 4);
            #pragma unroll
            for (int n = 0; n < NT; ++n)
                bf[csl][n].v = *(const s16x8*)(ldsB + (size_t)(buf * 4 + n * 2 + csl) * 512 + lane * 8);
        }
        __builtin_amdgcn_s_setprio(1);
        #pragma unroll
        for (int csl = 0; csl < 2; ++csl)
            #pragma unroll
            for (int n = 0; n < NT; ++n) {
                acc[n][0] = __builtin_amdgcn_mfma_f32_32x32x16_bf16(a[csl][0].v, bf[csl][n].v, acc[n][0], 0, 0, 0);
                acc[n][1] = __builtin_amdgcn_mfma_f32_32x32x16_bf16(a[csl][1].v, bf[csl][n].v, acc[n][1], 0, 0, 0);
            }
        __builtin_amdgcn_s_setprio(0);
        buf = (buf == 2) ? 0 : buf + 1;
    }

    // epilogue: d = s[pos] - 2*xp + p2[proto]; min over this wave's 64 positions
    // C layout (verified m74/m101): col = lane&31, row = (reg&3) + 8*(reg>>2) + 4*(lane>>5)
    #pragma unroll
    for (int n = 0; n < NT; ++n) {
        const int p7 = p7b + n;
        const float p2v = p2g[p7 * 32 + m];
        float dmin = 3.4e38f;
        #pragma unroll
        for (int reg = 0; reg < 16; ++reg) {
            const int row = (reg & 3) + 8 * (reg >> 2) + 4 * half;
            float d0 = sarr[wv * 64 + row]      - 2.f * acc[n][0][reg] + p2v;
            float d1 = sarr[wv * 64 + 32 + row] - 2.f * acc[n][1][reg] + p2v;
            dmin = fminf(dmin, fminf(d0, d1));
        }
        dmin = fminf(dmin, __shfl_xor(dmin, 32));   // merge the two half-wave row sets
        if (half == 0 && p7 * 32 + m < PN)
            atomicMin(&wsm[b * PN + p7 * 32 + m], (u32)__float_as_uint(fmaxf(dmin, 0.f)));
    }
}

// K1: block = (chunk of 256 positions, batch). Encoder once into LDS (position-major),
// then tap-decomposed MFMA GEMM, proto tiles in passes of 2+2+2+1, B staged per-block
// in triple-buffered LDS with depth-2 prefetch. 50368 B LDS -> 3 blocks/CU.
__global__ void __launch_bounds__(256, 3) k_dist(const float* __restrict__ x,
                                                 const float* __restrict__ we,
                                                 const float* __restrict__ waT,
                                                 const u16* __restrict__ pk,
                                                 u32* __restrict__ wsm,
                                                 const float* __restrict__ p2g) {
    __shared__ __align__(16) u16 fwin[WIN * FST];    // 36992 B, [slot][ch] bf16
    __shared__ __align__(16) u16 ldsB[3 * 4 * 512];  // 12288 B, 3 bufs x 4 chunks x 1KB
    __shared__ float gwin[WIN];                      // 1088 B; reused as sarr after phase 2

    const int t  = threadIdx.x;
    const int ck = blockIdx.x;           // 0..31
    const int b  = blockIdx.y;           // 0..31
    const int base = ck * CHK;
    const float* xb = x + (size_t)b * FIN * LIN;

    // Phase 1: f2 window (272 slots), position-major bf16 + f32 g
    enc_pos(base + t, t, xb, we, waT, (u32*)fwin, gwin);
    if (t < 16) enc_pos(base + CHK + t, CHK + t, xb, we, waT, (u32*)fwin, gwin);
    __syncthreads();

    // Phase 2: sliding patch-norm; result overwrites gwin (saves 1KB LDS).
    {
        float sv = 0.f;
        #pragma unroll
        for (int k = 0; k < PLEN; ++k) sv += gwin[t + k];
        sv = (base + t < LOV) ? sv : 3.0e38f;
        __syncthreads();                 // all gwin reads done before overwrite
        gwin[t] = sv;
    }
    __syncthreads();

    const int lane = t & 63;
    const int wv   = t >> 6;             // wave owns positions [wv*64, wv*64+64)

    dist_pass<2>(0, pk, fwin, ldsB, gwin, p2g, wsm, b, wv, lane);
    dist_pass<2>(2, pk, fwin, ldsB, gwin, p2g, wsm, b, wv, lane);
    dist_pass<2>(4, pk, fwin, ldsB, gwin, p2g, wsm, b, wv, lane);
    dist_pass<1>(6, pk, fwin, ldsB, gwin, p2g, wsm, b, wv, lane);
}

// K2: one block per batch; sole writer of d_out (f32: [0:320) logits, [320:6720) md).
__global__ void __launch_bounds__(256) k_head(const u32* __restrict__ wsm,
                                              const float* __restrict__ lw,
                                              float* __restrict__ out) {
    __shared__ float as_[PN];
    const int b = blockIdx.x, t = threadIdx.x;
    if (t < PN) {
        float md = __uint_as_float(wsm[b * PN + t]);
        md = fminf(fmaxf(md, 0.f), 2000.f);
        if (!(md == md)) md = 0.f;
        out[MD0 + b * PN + t] = md;
        as_[t] = logf((md + 1.f) / (md + EPSV));
    }
    __syncthreads();
    if (t < NCLS) {
        float sum = 0.f;
        #pragma unroll 1
        for (int p = 0; p < PN; ++p) sum += as_[p] * lw[t * PN + p];
        sum = fminf(fmaxf(sum, -100.f), 100.f);
        if (!(sum == sum)) sum = 0.f;
        out[b * NCLS + t] = sum;
    }
}

extern "C" void kernel_launch(void* const* d_in, const int* in_sizes, int n_in,
                              void* d_out, int out_size, void* d_ws, size_t ws_size,
                              hipStream_t stream) {
    // Inputs are FLOAT32. Resolve by unique element count (order-proof).
    const float* x  = 0;   // 32*16*8192 = 4194304
    const float* we = 0;   // 64*16*3    = 3072
    const float* wa = 0;   // 64*64*1    = 4096
    const float* pt = 0;   // 200*64*16  = 204800
    const float* lw = 0;   // 10*200     = 2000
    for (int i = 0; i < n_in; ++i) {
        switch (in_sizes[i]) {
            case 4194304: x  = (const float*)d_in[i]; break;
            case 3072:    we = (const float*)d_in[i]; break;
            case 4096:    wa = (const float*)d_in[i]; break;
            case 204800:  pt = (const float*)d_in[i]; break;
            case 2000:    lw = (const float*)d_in[i]; break;
            default: break;
        }
    }
    if (!x || !we || !wa || !pt || !lw) {
        x  = (const float*)d_in[0];
        we = (const float*)d_in[1];
        wa = (const float*)d_in[2];
        pt = (const float*)d_in[3];
        lw = (const float*)d_in[4];
    }
    float* out = (float*)d_out;            // f32: [0:320) logits, [320:6720) min_distances
    u32*   wsm = (u32*)d_ws;               // 6400 u32
    float* p2g = (float*)d_ws + B_ * PN;   // 224 f32
    float* waT = (float*)d_ws + B_ * PN + 224;            // 4096 f32
    u16*   pk  = (u16*)((float*)d_ws + B_ * PN + 224 + LAT * LAT);  // 458752 B (16B-aligned)

    k_init<<<dim3(64), dim3(256), 0, stream>>>(pt, wa, wsm, p2g, waT, pk);
    k_dist<<<dim3(32, 32), dim3(256), 0, stream>>>(x, we, waT, pk, wsm, p2g);
    k_head<<<dim3(B_), dim3(256), 0, stream>>>(wsm, lw, out);
}

// Round 6
// 232.998 us; speedup vs baseline: 1.6977x; 1.6977x over previous
//
#include <hip/hip_runtime.h>
#include <hip/hip_bf16.h>
#include <math.h>

// Problem constants
#define B_    32
#define FIN   16
#define LIN   8192
#define LAT   64
#define L1V   8190      // length after k=3 valid conv
#define PN    200
#define PLEN  16
#define LOV   8175      // L1V - 16 + 1
#define NCLS  10
#define EPSV  1e-4f
#define MD0   320       // f32 offset of min_distances in d_out
#define CHK   256       // positions per block
#define WIN   272       // window slots (CHK + 16)
#define FST   68        // fwin row stride in u16 (136 B: 2-way bank aliasing = free)
#define NPT   7         // proto tiles of 32 (200 padded to 224)
#define NFRAG (NPT * 16 * 4 * 64)   // 28672 pre-packed proto B-fragments
#define XSLOT 8256      // padded x slots per batch (zero tail; max read = 8225)

typedef unsigned short u16;
typedef unsigned int   u32;
typedef short s16x8 __attribute__((ext_vector_type(8)));   // 8 bf16 (4 VGPRs)
typedef float f32x16 __attribute__((ext_vector_type(16))); // 32x32 MFMA accumulator

union FragU { uint2 u2[2]; s16x8 v; };

__device__ __forceinline__ u16 vf2b(float f) {
    union { float f; u32 u; } v; v.f = f;
    u32 u = v.u;
    return (u16)((u + 0x7fffu + ((u >> 16) & 1u)) >> 16);   // RNE
}

// K0: wsm = FLT_MAX bits; p2g = ||proto||^2;
//     pk  = protos as per-lane MFMA B-frags (col=lane&31 proto, k=(lane>>5)*8+j ch, per tap/cs)
//     wpk = encoder B-frags: grp 0..5 = we[tap 0..2][ntile 0..1] (K=16 ci),
//                            grp 6..13 = wa[cs 0..3][ntile 0..1] (K=16 slice of 64 c_in)
//     xT  = x transposed to bf16 [b][slot][16 ci], slots zero-padded to XSLOT
__global__ void k_init(const float* __restrict__ x, const float* __restrict__ we,
                       const float* __restrict__ wa, const float* __restrict__ pt,
                       u32* __restrict__ wsm, float* __restrict__ p2g,
                       u16* __restrict__ pk, u16* __restrict__ wpk,
                       u16* __restrict__ xT) {
    const int tid = blockIdx.x * 256 + threadIdx.x;
    const int N   = gridDim.x * 256;

    for (int j = tid; j < B_ * PN; j += N) wsm[j] = 0x7f7fffffu;

    for (int p = tid; p < 224; p += N) {
        float s = 0.f;
        if (p < PN) {
            const float4* pr = (const float4*)(pt + (size_t)p * (LAT * PLEN));
            #pragma unroll 4
            for (int j = 0; j < 256; ++j) {
                float4 v = pr[j];
                s += v.x * v.x + v.y * v.y + v.z * v.z + v.w * v.w;
            }
        }
        p2g[p] = s;
    }

    for (int f = tid; f < NFRAG; f += N) {
        const int lane = f & 63;
        const int cs   = (f >> 6) & 3;
        const int tap  = (f >> 8) & 15;
        const int p7   = f >> 12;
        const int gp   = p7 * 32 + (lane & 31);
        const int chb  = cs * 16 + (lane >> 5) * 8;
        s16x8 v;
        if (gp < PN) {
            const float* src = pt + (size_t)gp * (LAT * PLEN) + (size_t)chb * PLEN + tap;
            #pragma unroll
            for (int j = 0; j < 8; ++j) v[j] = (short)vf2b(src[j * PLEN]);
        } else {
            #pragma unroll
            for (int j = 0; j < 8; ++j) v[j] = 0;
        }
        *(s16x8*)(pk + (size_t)f * 8) = v;
    }

    // wpk: 14 encoder B-frag groups x 64 lanes
    for (int f = tid; f < 14 * 64; f += N) {
        const int lane = f & 63, grp = f >> 6;
        const int col = lane & 31, kb = (lane >> 5) * 8;
        s16x8 v;
        if (grp < 6) {
            const int tau = grp >> 1, nt = grp & 1;
            #pragma unroll
            for (int j = 0; j < 8; ++j)
                v[j] = (short)vf2b(we[(size_t)(nt * 32 + col) * 48 + (kb + j) * 3 + tau]);
        } else {
            const int g2 = grp - 6, cs = g2 >> 1, nt = g2 & 1;
            #pragma unroll
            for (int j = 0; j < 8; ++j)
                v[j] = (short)vf2b(wa[(size_t)(nt * 32 + col) * 64 + cs * 16 + kb + j]);
        }
        *(s16x8*)(wpk + (size_t)f * 8) = v;
    }

    // xT transpose: u32 = (ci_odd<<16)|ci_even at [(b*XSLOT+slot)*8 + cp]
    u32* xT32 = (u32*)xT;
    const int TOT = B_ * XSLOT * 8;
    for (int i = tid; i < TOT; i += N) {
        const int cp   = i & 7;
        const int slot = (i >> 3) % XSLOT;
        const int b    = i / (XSLOT * 8);
        u32 w = 0;
        if (slot < LIN) {
            const float* xb = x + (size_t)b * FIN * LIN;
            float v0 = xb[(size_t)(cp * 2)     * LIN + slot];
            float v1 = xb[(size_t)(cp * 2 + 1) * LIN + slot];
            w = ((u32)vf2b(v1) << 16) | (u32)vf2b(v0);
        }
        xT32[i] = w;
    }
}

// K1: block = (chunk of 256 positions, batch).
// Phase 1 (NEW): encoder as MFMA. conv1 tap-decomposed (3 taps x K=16 ci) from xT,
//   f1 -> fwin (bf16); addon 1x1 (K=64, 4 cs) reads f1 from fwin IN PLACE (tile-private
//   rows, same wave -> no barrier) and overwrites with f2. 9 m-tiles of 32 rows,
//   wave w owns tiles {w, w+4, w+8}. Tile 8 rows >= 272 masked (A-read clamped).
//   Replaces 14336 VALU cy/wave with ~28 MFMA + ~64 ds_write_b16.
// Phase 2: g = ||f2||^2 per slot from fwin, then sliding 16-sum (gwin overwritten).
// Phase 3: distance GEMM = R1's proven structure, unchanged.
__global__ void __launch_bounds__(256, 4) k_dist(const u16* __restrict__ xT,
                                                 const u16* __restrict__ wpk,
                                                 const u16* __restrict__ pk,
                                                 u32* __restrict__ wsm,
                                                 const float* __restrict__ p2g) {
    __shared__ __align__(16) u16 fwin[WIN * FST];    // 36992 B, [slot][ch] bf16
    __shared__ float gwin[WIN];                      // 1088 B; g then s (total 38080 -> 4 blk/CU)

    const int t  = threadIdx.x;
    const int ck = blockIdx.x;           // 0..31
    const int b  = blockIdx.y;           // 0..31
    const int base = ck * CHK;

    const int lane = t & 63;
    const int wv   = t >> 6;
    const int m    = lane & 31;
    const int half = lane >> 5;
    const int koff = half * 8;

    const u16* wpkl = wpk + (size_t)lane * 8;
    const u16* xTb  = xT + (size_t)b * XSLOT * 16;

    // ---------------- Phase 1: MFMA encoder ----------------
    #pragma unroll 1
    for (int mt = wv; mt < 9; mt += 4) {
        const int ar = mt * 32 + m;                  // this lane's A row
        // GEMM1: f1 = relu(conv3(x)), tap-decomposed, K=16 ci per tap
        f32x16 c1[2];
        #pragma unroll
        for (int i = 0; i < 16; ++i) { c1[0][i] = 0.f; c1[1][i] = 0.f; }
        #pragma unroll
        for (int tau = 0; tau < 3; ++tau) {
            FragU aF;
            aF.v = *(const s16x8*)(xTb + (size_t)(base + ar + tau) * 16 + koff);
            #pragma unroll
            for (int nt = 0; nt < 2; ++nt) {
                FragU bW; bW.v = *(const s16x8*)(wpkl + (size_t)(tau * 2 + nt) * 512);
                c1[nt] = __builtin_amdgcn_mfma_f32_32x32x16_bf16(aF.v, bW.v, c1[nt], 0, 0, 0);
            }
        }
        // write f1 (relu, bf16) into fwin rows of this tile (mask rows >= WIN for tile 8)
        #pragma unroll
        for (int nt = 0; nt < 2; ++nt) {
            const int col = nt * 32 + m;
            #pragma unroll
            for (int reg = 0; reg < 16; ++reg) {
                const int row = mt * 32 + (reg & 3) + 8 * (reg >> 2) + 4 * half;
                if (row < WIN) fwin[row * FST + col] = vf2b(fmaxf(c1[nt][reg], 0.f));
            }
        }
        // GEMM2: f2 = relu(wa . f1), K=64 in 4 cs slices; reads then overwrites same rows
        f32x16 c2[2];
        #pragma unroll
        for (int i = 0; i < 16; ++i) { c2[0][i] = 0.f; c2[1][i] = 0.f; }
        FragU a2[4];
        const int arc = (ar < WIN) ? ar : (WIN - 1);     // clamp tile-8 dead rows (stay in tile)
        #pragma unroll
        for (int cs = 0; cs < 4; ++cs) {
            const u16* ap = &fwin[arc * FST + cs * 16 + koff];
            a2[cs].u2[0] = *(const uint2*)ap;
            a2[cs].u2[1] = *(const uint2*)(ap + 4);
        }
        #pragma unroll
        for (int cs = 0; cs < 4; ++cs)
            #pragma unroll
            for (int nt = 0; nt < 2; ++nt) {
                FragU bW; bW.v = *(const s16x8*)(wpkl + (size_t)(6 + cs * 2 + nt) * 512);
                c2[nt] = __builtin_amdgcn_mfma_f32_32x32x16_bf16(a2[cs].v, bW.v, c2[nt], 0, 0, 0);
            }
        #pragma unroll
        for (int nt = 0; nt < 2; ++nt) {
            const int col = nt * 32 + m;
            #pragma unroll
            for (int reg = 0; reg < 16; ++reg) {
                const int row = mt * 32 + (reg & 3) + 8 * (reg >> 2) + 4 * half;
                if (row < WIN) fwin[row * FST + col] = vf2b(fmaxf(c2[nt][reg], 0.f));
            }
        }
    }
    __syncthreads();

    // ---------------- Phase 2a: per-slot g = ||f2||^2 ----------------
    {
        float g0 = 0.f, g1 = 0.f;
        const uint2* r0 = (const uint2*)(fwin + (size_t)t * FST);
        #pragma unroll
        for (int i = 0; i < 16; ++i) {
            uint2 v = r0[i];
            float a = __uint_as_float(v.x << 16);
            float bb = __uint_as_float(v.x & 0xffff0000u);
            float c = __uint_as_float(v.y << 16);
            float d = __uint_as_float(v.y & 0xffff0000u);
            g0 += a * a + bb * bb + c * c + d * d;
        }
        if (t < 16) {
            const uint2* r1 = (const uint2*)(fwin + (size_t)(CHK + t) * FST);
            #pragma unroll
            for (int i = 0; i < 16; ++i) {
                uint2 v = r1[i];
                float a = __uint_as_float(v.x << 16);
                float bb = __uint_as_float(v.x & 0xffff0000u);
                float c = __uint_as_float(v.y << 16);
                float d = __uint_as_float(v.y & 0xffff0000u);
                g1 += a * a + bb * bb + c * c + d * d;
            }
        }
        gwin[t] = g0;
        if (t < 16) gwin[CHK + t] = g1;
    }
    __syncthreads();

    // ---------------- Phase 2b: sliding patch-norm (poison tail), overwrite gwin ----
    {
        float sv = 0.f;
        #pragma unroll
        for (int k = 0; k < PLEN; ++k) sv += gwin[t + k];
        sv = (base + t < LOV) ? sv : 3.0e38f;
        __syncthreads();
        gwin[t] = sv;
    }
    __syncthreads();

    // ---------------- Phase 3: distance GEMM (R1 structure, unchanged) ----------------
    #pragma unroll 1
    for (int p7 = 0; p7 < NPT; ++p7) {
        f32x16 acc0, acc1;
        #pragma unroll
        for (int i = 0; i < 16; ++i) { acc0[i] = 0.f; acc1[i] = 0.f; }

        const u16* pkb = pk + (size_t)p7 * (16 * 4 * 64 * 8) + (size_t)lane * 8;

        #pragma unroll 2
        for (int tap = 0; tap < 16; ++tap) {
            #pragma unroll
            for (int cs = 0; cs < 4; ++cs) {
                FragU bF, a0, a1;
                bF.v = *(const s16x8*)(pkb + (size_t)(tap * 4 + cs) * 512);
                const int co = cs * 16 + koff;
                const u16* ap = &fwin[(wv * 64 + m + tap) * FST + co];
                a0.u2[0] = *(const uint2*)ap; a0.u2[1] = *(const uint2*)(ap + 4);
                const u16* aq = ap + 32 * FST;
                a1.u2[0] = *(const uint2*)aq; a1.u2[1] = *(const uint2*)(aq + 4);
                acc0 = __builtin_amdgcn_mfma_f32_32x32x16_bf16(a0.v, bF.v, acc0, 0, 0, 0);
                acc1 = __builtin_amdgcn_mfma_f32_32x32x16_bf16(a1.v, bF.v, acc1, 0, 0, 0);
            }
        }

        // epilogue: d = s[pos] - 2*xp + p2[proto]; min over this wave's 64 positions
        // C layout (verified m74/m101): col = lane&31, row = (reg&3) + 8*(reg>>2) + 4*(lane>>5)
        const float p2v = p2g[p7 * 32 + m];
        float dmin = 3.4e38f;
        #pragma unroll
        for (int reg = 0; reg < 16; ++reg) {
            const int row = (reg & 3) + 8 * (reg >> 2) + 4 * half;
            float d0 = gwin[wv * 64 + row]      - 2.f * acc0[reg] + p2v;
            float d1 = gwin[wv * 64 + 32 + row] - 2.f * acc1[reg] + p2v;
            dmin = fminf(dmin, fminf(d0, d1));
        }
        dmin = fminf(dmin, __shfl_xor(dmin, 32));   // merge the two half-wave row sets
        if (half == 0 && p7 * 32 + m < PN)
            atomicMin(&wsm[b * PN + p7 * 32 + m], (u32)__float_as_uint(fmaxf(dmin, 0.f)));
    }
}

// K2: one block per batch; sole writer of d_out (f32: [0:320) logits, [320:6720) md).
__global__ void __launch_bounds__(256) k_head(const u32* __restrict__ wsm,
                                              const float* __restrict__ lw,
                                              float* __restrict__ out) {
    __shared__ float as_[PN];
    const int b = blockIdx.x, t = threadIdx.x;
    if (t < PN) {
        float md = __uint_as_float(wsm[b * PN + t]);
        md = fminf(fmaxf(md, 0.f), 2000.f);
        if (!(md == md)) md = 0.f;
        out[MD0 + b * PN + t] = md;
        as_[t] = logf((md + 1.f) / (md + EPSV));
    }
    __syncthreads();
    if (t < NCLS) {
        float sum = 0.f;
        #pragma unroll 1
        for (int p = 0; p < PN; ++p) sum += as_[p] * lw[t * PN + p];
        sum = fminf(fmaxf(sum, -100.f), 100.f);
        if (!(sum == sum)) sum = 0.f;
        out[b * NCLS + t] = sum;
    }
}

extern "C" void kernel_launch(void* const* d_in, const int* in_sizes, int n_in,
                              void* d_out, int out_size, void* d_ws, size_t ws_size,
                              hipStream_t stream) {
    // Inputs are FLOAT32. Resolve by unique element count (order-proof).
    const float* x  = 0;   // 32*16*8192 = 4194304
    const float* we = 0;   // 64*16*3    = 3072
    const float* wa = 0;   // 64*64*1    = 4096
    const float* pt = 0;   // 200*64*16  = 204800
    const float* lw = 0;   // 10*200     = 2000
    for (int i = 0; i < n_in; ++i) {
        switch (in_sizes[i]) {
            case 4194304: x  = (const float*)d_in[i]; break;
            case 3072:    we = (const float*)d_in[i]; break;
            case 4096:    wa = (const float*)d_in[i]; break;
            case 204800:  pt = (const float*)d_in[i]; break;
            case 2000:    lw = (const float*)d_in[i]; break;
            default: break;
        }
    }
    if (!x || !we || !wa || !pt || !lw) {
        x  = (const float*)d_in[0];
        we = (const float*)d_in[1];
        wa = (const float*)d_in[2];
        pt = (const float*)d_in[3];
        lw = (const float*)d_in[4];
    }
    float* out = (float*)d_out;   // f32: [0:320) logits, [320:6720) min_distances

    // Workspace layout (all 16B-aligned):
    char* ws  = (char*)d_ws;
    u32*   wsm = (u32*)ws;                 // 25600 B
    float* p2g = (float*)(ws + 25600);     // 896 B   -> 26496
    u16*   pk  = (u16*)(ws + 26496);       // 917504  -> 944000
    u16*   wpk = (u16*)(ws + 944000);      // 14336   -> 958336
    u16*   xT  = (u16*)(ws + 958336);      // 8454144 -> 9412480 (~9.0 MB total)

    k_init<<<dim3(256), dim3(256), 0, stream>>>(x, we, wa, pt, wsm, p2g, pk, wpk, xT);
    k_dist<<<dim3(32, 32), dim3(256), 0, stream>>>(xT, wpk, pk, wsm, p2g);
    k_head<<<dim3(B_), dim3(256), 0, stream>>>(wsm, lw, out);
}

// Round 7
// 229.652 us; speedup vs baseline: 1.7225x; 1.0146x over previous
//
#include <hip/hip_runtime.h>
#include <hip/hip_bf16.h>
#include <math.h>

// Problem constants
#define B_    32
#define FIN   16
#define LIN   8192
#define LAT   64
#define L1V   8190      // length after k=3 valid conv
#define PN    200
#define PLEN  16
#define LOV   8175      // L1V - 16 + 1
#define NCLS  10
#define EPSV  1e-4f
#define MD0   320       // f32 offset of min_distances in d_out
#define CHK   256       // positions per block
#define WIN   272       // window slots (CHK + 16)
#define FST   68        // fwin row stride in u16 (136 B: 2-way bank aliasing = free)
#define NPT   7         // proto tiles of 32 (200 padded to 224)
#define NFRAG (NPT * 16 * 4 * 64)   // 28672 pre-packed proto B-fragments
#define XSLOT 8256      // padded x slots per batch (zero tail; max read = 8225)
#define NTRB  (33 * B_) // transpose blocks: 33 tiles of 256 slots x 32 batches

typedef unsigned short u16;
typedef unsigned int   u32;
typedef short s16x8 __attribute__((ext_vector_type(8)));   // 8 bf16 (4 VGPRs)
typedef float f32x16 __attribute__((ext_vector_type(16))); // 32x32 MFMA accumulator

union FragU { uint2 u2[2]; s16x8 v; };

__device__ __forceinline__ u16 vf2b(float f) {
    union { float f; u32 u; } v; v.f = f;
    u32 u = v.u;
    return (u16)((u + 0x7fffu + ((u >> 16) & 1u)) >> 16);   // RNE
}

// K0 (fused prep):
//  blocks [0, NTRB): LDS-tiled transpose x -> xT bf16 [b][slot][16 ci], zero-padded.
//    Read: per channel, 256 consecutive f32 (coalesced 1KB). Write: 32 B/thread
//    contiguous (coalesced 8KB/block). Replaces R6's scattered-gather transpose
//    (the ~70-100us hidden cost between k_dist rounds).
//  blocks [NTRB, NTRB+64): wsm = FLT_MAX bits; p2g = ||proto||^2; pk/wpk B-frag packs.
__global__ void k_prep(const float* __restrict__ x, const float* __restrict__ we,
                       const float* __restrict__ wa, const float* __restrict__ pt,
                       u32* __restrict__ wsm, float* __restrict__ p2g,
                       u16* __restrict__ pk, u16* __restrict__ wpk,
                       u16* __restrict__ xT) {
    __shared__ u16 ls[16][256];          // 8 KB (transpose blocks only)
    const int t = threadIdx.x;

    if (blockIdx.x < NTRB) {
        // ---- coalesced transpose tile: batch b, slots [base, base+256) ----
        const int tile = blockIdx.x % 33;
        const int b    = blockIdx.x / 33;
        const int base = tile * 256;
        const float* xb = x + (size_t)b * FIN * LIN;
        const int slot = base + t;
        #pragma unroll
        for (int ch = 0; ch < 16; ++ch) {
            float v = (slot < LIN) ? xb[(size_t)ch * LIN + slot] : 0.f;
            ls[ch][t] = vf2b(v);         // bank-free: 2 lanes/bank aliasing
        }
        __syncthreads();
        if (slot < XSLOT) {
            u32 w[8];
            #pragma unroll
            for (int cp = 0; cp < 8; ++cp)
                w[cp] = ((u32)ls[2 * cp + 1][t] << 16) | (u32)ls[2 * cp][t];
            uint4* dst = (uint4*)(xT + ((size_t)b * XSLOT + slot) * 16);
            dst[0] = make_uint4(w[0], w[1], w[2], w[3]);
            dst[1] = make_uint4(w[4], w[5], w[6], w[7]);
        }
        return;
    }

    // ---- misc packing (grid-strided over 64 blocks x 256 threads) ----
    const int tid = (blockIdx.x - NTRB) * 256 + t;
    const int N   = 64 * 256;

    for (int j = tid; j < B_ * PN; j += N) wsm[j] = 0x7f7fffffu;

    for (int p = tid; p < 224; p += N) {
        float s = 0.f;
        if (p < PN) {
            const float4* pr = (const float4*)(pt + (size_t)p * (LAT * PLEN));
            #pragma unroll 4
            for (int j = 0; j < 256; ++j) {
                float4 v = pr[j];
                s += v.x * v.x + v.y * v.y + v.z * v.z + v.w * v.w;
            }
        }
        p2g[p] = s;
    }

    // pk: protos as per-lane MFMA B-frags (col=lane&31 proto, k=(lane>>5)*8+j ch, per tap/cs)
    for (int f = tid; f < NFRAG; f += N) {
        const int lane = f & 63;
        const int cs   = (f >> 6) & 3;
        const int tap  = (f >> 8) & 15;
        const int p7   = f >> 12;
        const int gp   = p7 * 32 + (lane & 31);
        const int chb  = cs * 16 + (lane >> 5) * 8;
        s16x8 v;
        if (gp < PN) {
            const float* src = pt + (size_t)gp * (LAT * PLEN) + (size_t)chb * PLEN + tap;
            #pragma unroll
            for (int j = 0; j < 8; ++j) v[j] = (short)vf2b(src[j * PLEN]);
        } else {
            #pragma unroll
            for (int j = 0; j < 8; ++j) v[j] = 0;
        }
        *(s16x8*)(pk + (size_t)f * 8) = v;
    }

    // wpk: 14 encoder B-frag groups x 64 lanes
    // grp 0..5 = we[tap 0..2][ntile 0..1] (K=16 ci); grp 6..13 = wa[cs 0..3][ntile 0..1]
    for (int f = tid; f < 14 * 64; f += N) {
        const int lane = f & 63, grp = f >> 6;
        const int col = lane & 31, kb = (lane >> 5) * 8;
        s16x8 v;
        if (grp < 6) {
            const int tau = grp >> 1, nt = grp & 1;
            #pragma unroll
            for (int j = 0; j < 8; ++j)
                v[j] = (short)vf2b(we[(size_t)(nt * 32 + col) * 48 + (kb + j) * 3 + tau]);
        } else {
            const int g2 = grp - 6, cs = g2 >> 1, nt = g2 & 1;
            #pragma unroll
            for (int j = 0; j < 8; ++j)
                v[j] = (short)vf2b(wa[(size_t)(nt * 32 + col) * 64 + cs * 16 + kb + j]);
        }
        *(s16x8*)(wpk + (size_t)f * 8) = v;
    }
}

// K1: block = (chunk of 256 positions, batch).  [unchanged from R6]
// Phase 1: encoder as MFMA. conv1 tap-decomposed (3 taps x K=16 ci) from xT,
//   f1 -> fwin (bf16); addon 1x1 (K=64, 4 cs) reads f1 from fwin IN PLACE (tile-private
//   rows, same wave -> no barrier) and overwrites with f2. 9 m-tiles of 32 rows,
//   wave w owns tiles {w, w+4, w+8}.
// Phase 2: g = ||f2||^2 per slot from fwin, then sliding 16-sum (gwin overwritten).
// Phase 3: distance GEMM (R1's proven structure).
__global__ void __launch_bounds__(256, 4) k_dist(const u16* __restrict__ xT,
                                                 const u16* __restrict__ wpk,
                                                 const u16* __restrict__ pk,
                                                 u32* __restrict__ wsm,
                                                 const float* __restrict__ p2g) {
    __shared__ __align__(16) u16 fwin[WIN * FST];    // 36992 B, [slot][ch] bf16
    __shared__ float gwin[WIN];                      // 1088 B; g then s (total 38080 -> 4 blk/CU)

    const int t  = threadIdx.x;
    const int ck = blockIdx.x;           // 0..31
    const int b  = blockIdx.y;           // 0..31
    const int base = ck * CHK;

    const int lane = t & 63;
    const int wv   = t >> 6;
    const int m    = lane & 31;
    const int half = lane >> 5;
    const int koff = half * 8;

    const u16* wpkl = wpk + (size_t)lane * 8;
    const u16* xTb  = xT + (size_t)b * XSLOT * 16;

    // ---------------- Phase 1: MFMA encoder ----------------
    #pragma unroll 1
    for (int mt = wv; mt < 9; mt += 4) {
        const int ar = mt * 32 + m;                  // this lane's A row
        // GEMM1: f1 = relu(conv3(x)), tap-decomposed, K=16 ci per tap
        f32x16 c1[2];
        #pragma unroll
        for (int i = 0; i < 16; ++i) { c1[0][i] = 0.f; c1[1][i] = 0.f; }
        #pragma unroll
        for (int tau = 0; tau < 3; ++tau) {
            FragU aF;
            aF.v = *(const s16x8*)(xTb + (size_t)(base + ar + tau) * 16 + koff);
            #pragma unroll
            for (int nt = 0; nt < 2; ++nt) {
                FragU bW; bW.v = *(const s16x8*)(wpkl + (size_t)(tau * 2 + nt) * 512);
                c1[nt] = __builtin_amdgcn_mfma_f32_32x32x16_bf16(aF.v, bW.v, c1[nt], 0, 0, 0);
            }
        }
        // write f1 (relu, bf16) into fwin rows of this tile (mask rows >= WIN for tile 8)
        #pragma unroll
        for (int nt = 0; nt < 2; ++nt) {
            const int col = nt * 32 + m;
            #pragma unroll
            for (int reg = 0; reg < 16; ++reg) {
                const int row = mt * 32 + (reg & 3) + 8 * (reg >> 2) + 4 * half;
                if (row < WIN) fwin[row * FST + col] = vf2b(fmaxf(c1[nt][reg], 0.f));
            }
        }
        // GEMM2: f2 = relu(wa . f1), K=64 in 4 cs slices; reads then overwrites same rows
        f32x16 c2[2];
        #pragma unroll
        for (int i = 0; i < 16; ++i) { c2[0][i] = 0.f; c2[1][i] = 0.f; }
        FragU a2[4];
        const int arc = (ar < WIN) ? ar : (WIN - 1);     // clamp tile-8 dead rows (stay in tile)
        #pragma unroll
        for (int cs = 0; cs < 4; ++cs) {
            const u16* ap = &fwin[arc * FST + cs * 16 + koff];
            a2[cs].u2[0] = *(const uint2*)ap;
            a2[cs].u2[1] = *(const uint2*)(ap + 4);
        }
        #pragma unroll
        for (int cs = 0; cs < 4; ++cs)
            #pragma unroll
            for (int nt = 0; nt < 2; ++nt) {
                FragU bW; bW.v = *(const s16x8*)(wpkl + (size_t)(6 + cs * 2 + nt) * 512);
                c2[nt] = __builtin_amdgcn_mfma_f32_32x32x16_bf16(a2[cs].v, bW.v, c2[nt], 0, 0, 0);
            }
        #pragma unroll
        for (int nt = 0; nt < 2; ++nt) {
            const int col = nt * 32 + m;
            #pragma unroll
            for (int reg = 0; reg < 16; ++reg) {
                const int row = mt * 32 + (reg & 3) + 8 * (reg >> 2) + 4 * half;
                if (row < WIN) fwin[row * FST + col] = vf2b(fmaxf(c2[nt][reg], 0.f));
            }
        }
    }
    __syncthreads();

    // ---------------- Phase 2a: per-slot g = ||f2||^2 ----------------
    {
        float g0 = 0.f, g1 = 0.f;
        const uint2* r0 = (const uint2*)(fwin + (size_t)t * FST);
        #pragma unroll
        for (int i = 0; i < 16; ++i) {
            uint2 v = r0[i];
            float a = __uint_as_float(v.x << 16);
            float bb = __uint_as_float(v.x & 0xffff0000u);
            float c = __uint_as_float(v.y << 16);
            float d = __uint_as_float(v.y & 0xffff0000u);
            g0 += a * a + bb * bb + c * c + d * d;
        }
        if (t < 16) {
            const uint2* r1 = (const uint2*)(fwin + (size_t)(CHK + t) * FST);
            #pragma unroll
            for (int i = 0; i < 16; ++i) {
                uint2 v = r1[i];
                float a = __uint_as_float(v.x << 16);
                float bb = __uint_as_float(v.x & 0xffff0000u);
                float c = __uint_as_float(v.y << 16);
                float d = __uint_as_float(v.y & 0xffff0000u);
                g1 += a * a + bb * bb + c * c + d * d;
            }
        }
        gwin[t] = g0;
        if (t < 16) gwin[CHK + t] = g1;
    }
    __syncthreads();

    // ---------------- Phase 2b: sliding patch-norm (poison tail), overwrite gwin ----
    {
        float sv = 0.f;
        #pragma unroll
        for (int k = 0; k < PLEN; ++k) sv += gwin[t + k];
        sv = (base + t < LOV) ? sv : 3.0e38f;
        __syncthreads();
        gwin[t] = sv;
    }
    __syncthreads();

    // ---------------- Phase 3: distance GEMM ----------------
    #pragma unroll 1
    for (int p7 = 0; p7 < NPT; ++p7) {
        f32x16 acc0, acc1;
        #pragma unroll
        for (int i = 0; i < 16; ++i) { acc0[i] = 0.f; acc1[i] = 0.f; }

        const u16* pkb = pk + (size_t)p7 * (16 * 4 * 64 * 8) + (size_t)lane * 8;

        #pragma unroll 2
        for (int tap = 0; tap < 16; ++tap) {
            #pragma unroll
            for (int cs = 0; cs < 4; ++cs) {
                FragU bF, a0, a1;
                bF.v = *(const s16x8*)(pkb + (size_t)(tap * 4 + cs) * 512);
                const int co = cs * 16 + koff;
                const u16* ap = &fwin[(wv * 64 + m + tap) * FST + co];
                a0.u2[0] = *(const uint2*)ap; a0.u2[1] = *(const uint2*)(ap + 4);
                const u16* aq = ap + 32 * FST;
                a1.u2[0] = *(const uint2*)aq; a1.u2[1] = *(const uint2*)(aq + 4);
                acc0 = __builtin_amdgcn_mfma_f32_32x32x16_bf16(a0.v, bF.v, acc0, 0, 0, 0);
                acc1 = __builtin_amdgcn_mfma_f32_32x32x16_bf16(a1.v, bF.v, acc1, 0, 0, 0);
            }
        }

        // epilogue: d = s[pos] - 2*xp + p2[proto]; min over this wave's 64 positions
        // C layout (verified m74/m101): col = lane&31, row = (reg&3) + 8*(reg>>2) + 4*(lane>>5)
        const float p2v = p2g[p7 * 32 + m];
        float dmin = 3.4e38f;
        #pragma unroll
        for (int reg = 0; reg < 16; ++reg) {
            const int row = (reg & 3) + 8 * (reg >> 2) + 4 * half;
            float d0 = gwin[wv * 64 + row]      - 2.f * acc0[reg] + p2v;
            float d1 = gwin[wv * 64 + 32 + row] - 2.f * acc1[reg] + p2v;
            dmin = fminf(dmin, fminf(d0, d1));
        }
        dmin = fminf(dmin, __shfl_xor(dmin, 32));   // merge the two half-wave row sets
        if (half == 0 && p7 * 32 + m < PN)
            atomicMin(&wsm[b * PN + p7 * 32 + m], (u32)__float_as_uint(fmaxf(dmin, 0.f)));
    }
}

// K2: one block per batch; sole writer of d_out (f32: [0:320) logits, [320:6720) md).
__global__ void __launch_bounds__(256) k_head(const u32* __restrict__ wsm,
                                              const float* __restrict__ lw,
                                              float* __restrict__ out) {
    __shared__ float as_[PN];
    const int b = blockIdx.x, t = threadIdx.x;
    if (t < PN) {
        float md = __uint_as_float(wsm[b * PN + t]);
        md = fminf(fmaxf(md, 0.f), 2000.f);
        if (!(md == md)) md = 0.f;
        out[MD0 + b * PN + t] = md;
        as_[t] = logf((md + 1.f) / (md + EPSV));
    }
    __syncthreads();
    if (t < NCLS) {
        float sum = 0.f;
        #pragma unroll 1
        for (int p = 0; p < PN; ++p) sum += as_[p] * lw[t * PN + p];
        sum = fminf(fmaxf(sum, -100.f), 100.f);
        if (!(sum == sum)) sum = 0.f;
        out[b * NCLS + t] = sum;
    }
}

extern "C" void kernel_launch(void* const* d_in, const int* in_sizes, int n_in,
                              void* d_out, int out_size, void* d_ws, size_t ws_size,
                              hipStream_t stream) {
    // Inputs are FLOAT32. Resolve by unique element count (order-proof).
    const float* x  = 0;   // 32*16*8192 = 4194304
    const float* we = 0;   // 64*16*3    = 3072
    const float* wa = 0;   // 64*64*1    = 4096
    const float* pt = 0;   // 200*64*16  = 204800
    const float* lw = 0;   // 10*200     = 2000
    for (int i = 0; i < n_in; ++i) {
        switch (in_sizes[i]) {
            case 4194304: x  = (const float*)d_in[i]; break;
            case 3072:    we = (const float*)d_in[i]; break;
            case 4096:    wa = (const float*)d_in[i]; break;
            case 204800:  pt = (const float*)d_in[i]; break;
            case 2000:    lw = (const float*)d_in[i]; break;
            default: break;
        }
    }
    if (!x || !we || !wa || !pt || !lw) {
        x  = (const float*)d_in[0];
        we = (const float*)d_in[1];
        wa = (const float*)d_in[2];
        pt = (const float*)d_in[3];
        lw = (const float*)d_in[4];
    }
    float* out = (float*)d_out;   // f32: [0:320) logits, [320:6720) min_distances

    // Workspace layout (all 16B-aligned):
    char* ws  = (char*)d_ws;
    u32*   wsm = (u32*)ws;                 // 25600 B
    float* p2g = (float*)(ws + 25600);     // 896 B   -> 26496
    u16*   pk  = (u16*)(ws + 26496);       // 917504  -> 944000
    u16*   wpk = (u16*)(ws + 944000);      // 14336   -> 958336
    u16*   xT  = (u16*)(ws + 958336);      // 8454144 -> 9412480 (~9.0 MB total)

    k_prep<<<dim3(NTRB + 64), dim3(256), 0, stream>>>(x, we, wa, pt, wsm, p2g, pk, wpk, xT);
    k_dist<<<dim3(32, 32), dim3(256), 0, stream>>>(xT, wpk, pk, wsm, p2g);
    k_head<<<dim3(B_), dim3(256), 0, stream>>>(wsm, lw, out);
}

// Round 8
// 221.275 us; speedup vs baseline: 1.7877x; 1.0379x over previous
//
#include <hip/hip_runtime.h>
#include <hip/hip_bf16.h>
#include <math.h>

// Problem constants
#define B_    32
#define FIN   16
#define LIN   8192
#define LAT   64
#define L1V   8190      // length after k=3 valid conv
#define PN    200
#define PLEN  16
#define LOV   8175      // L1V - 16 + 1
#define NCLS  10
#define EPSV  1e-4f
#define MD0   320       // f32 offset of min_distances in d_out
#define CHK   512       // positions per block (R8: doubled -> per-CU B traffic halves)
#define WIN   528       // window slots (CHK + 16)
#define FST   68        // fwin row stride in u16 (136 B: 2-way bank aliasing = free)
#define NPT   7         // proto tiles of 32 (200 padded to 224)
#define NFRAG (NPT * 16 * 4 * 64)   // 28672 pre-packed proto B-fragments
#define XSLOT 8256      // padded x slots per batch (zero tail; max read = 8225)
#define NTRB  (33 * B_) // transpose blocks: 33 tiles of 256 slots x 32 batches

typedef unsigned short u16;
typedef unsigned int   u32;
typedef short s16x8 __attribute__((ext_vector_type(8)));   // 8 bf16 (4 VGPRs)
typedef float f32x16 __attribute__((ext_vector_type(16))); // 32x32 MFMA accumulator

union FragU { uint2 u2[2]; s16x8 v; };

__device__ __forceinline__ u16 vf2b(float f) {
    union { float f; u32 u; } v; v.f = f;
    u32 u = v.u;
    return (u16)((u + 0x7fffu + ((u >> 16) & 1u)) >> 16);   // RNE
}

// K0 (fused prep):
//  blocks [0, NTRB): LDS-tiled transpose x -> xT bf16 [b][slot][16 ci], zero-padded.
//  blocks [NTRB, NTRB+64): wsm = FLT_MAX bits; cnt = 0; p2g = ||proto||^2 (wave-parallel);
//                          pk/wpk B-frag packs.
__global__ void k_prep(const float* __restrict__ x, const float* __restrict__ we,
                       const float* __restrict__ wa, const float* __restrict__ pt,
                       u32* __restrict__ wsm, u32* __restrict__ cnt,
                       float* __restrict__ p2g,
                       u16* __restrict__ pk, u16* __restrict__ wpk,
                       u16* __restrict__ xT) {
    __shared__ u16 ls[16][256];          // 8 KB (transpose blocks only)
    const int t = threadIdx.x;

    if (blockIdx.x < NTRB) {
        // ---- coalesced transpose tile: batch b, slots [base, base+256) ----
        const int tile = blockIdx.x % 33;
        const int b    = blockIdx.x / 33;
        const int base = tile * 256;
        const float* xb = x + (size_t)b * FIN * LIN;
        const int slot = base + t;
        #pragma unroll
        for (int ch = 0; ch < 16; ++ch) {
            float v = (slot < LIN) ? xb[(size_t)ch * LIN + slot] : 0.f;
            ls[ch][t] = vf2b(v);
        }
        __syncthreads();
        if (slot < XSLOT) {
            u32 w[8];
            #pragma unroll
            for (int cp = 0; cp < 8; ++cp)
                w[cp] = ((u32)ls[2 * cp + 1][t] << 16) | (u32)ls[2 * cp][t];
            uint4* dst = (uint4*)(xT + ((size_t)b * XSLOT + slot) * 16);
            dst[0] = make_uint4(w[0], w[1], w[2], w[3]);
            dst[1] = make_uint4(w[4], w[5], w[6], w[7]);
        }
        return;
    }

    // ---- misc packing (grid-strided over 64 blocks x 256 threads) ----
    const int tid = (blockIdx.x - NTRB) * 256 + t;
    const int N   = 64 * 256;

    for (int j = tid; j < B_ * PN; j += N) wsm[j] = 0x7f7fffffu;
    for (int j = tid; j < B_; j += N) cnt[j] = 0;

    // p2g wave-parallel: one wave per proto, lane sums 16 f32, butterfly reduce
    {
        const int wid = tid >> 6, nl = tid & 63, NW = N >> 6;
        for (int p = wid; p < 224; p += NW) {
            float s = 0.f;
            if (p < PN) {
                const float4* pr = (const float4*)(pt + (size_t)p * (LAT * PLEN)) + nl * 4;
                #pragma unroll
                for (int j = 0; j < 4; ++j) {
                    float4 v = pr[j];
                    s += v.x * v.x + v.y * v.y + v.z * v.z + v.w * v.w;
                }
            }
            #pragma unroll
            for (int off = 32; off; off >>= 1) s += __shfl_xor(s, off);
            if (nl == 0) p2g[p] = s;
        }
    }

    // pk: protos as per-lane MFMA B-frags (col=lane&31 proto, k=(lane>>5)*8+j ch, per tap/cs)
    for (int f = tid; f < NFRAG; f += N) {
        const int lane = f & 63;
        const int cs   = (f >> 6) & 3;
        const int tap  = (f >> 8) & 15;
        const int p7   = f >> 12;
        const int gp   = p7 * 32 + (lane & 31);
        const int chb  = cs * 16 + (lane >> 5) * 8;
        s16x8 v;
        if (gp < PN) {
            const float* src = pt + (size_t)gp * (LAT * PLEN) + (size_t)chb * PLEN + tap;
            #pragma unroll
            for (int j = 0; j < 8; ++j) v[j] = (short)vf2b(src[j * PLEN]);
        } else {
            #pragma unroll
            for (int j = 0; j < 8; ++j) v[j] = 0;
        }
        *(s16x8*)(pk + (size_t)f * 8) = v;
    }

    // wpk: 14 encoder B-frag groups x 64 lanes
    for (int f = tid; f < 14 * 64; f += N) {
        const int lane = f & 63, grp = f >> 6;
        const int col = lane & 31, kb = (lane >> 5) * 8;
        s16x8 v;
        if (grp < 6) {
            const int tau = grp >> 1, nt = grp & 1;
            #pragma unroll
            for (int j = 0; j < 8; ++j)
                v[j] = (short)vf2b(we[(size_t)(nt * 32 + col) * 48 + (kb + j) * 3 + tau]);
        } else {
            const int g2 = grp - 6, cs = g2 >> 1, nt = g2 & 1;
            #pragma unroll
            for (int j = 0; j < 8; ++j)
                v[j] = (short)vf2b(wa[(size_t)(nt * 32 + col) * 64 + cs * 16 + kb + j]);
        }
        *(s16x8*)(wpk + (size_t)f * 8) = v;
    }
}

// One pass over NT proto-tiles, wave-M = 128 positions (4 row-groups of 32).
// Per (tap,cs): 4 A ds_reads + NT B global loads + 4*NT MFMA -> 8 MFMAs of cover
// per B-load at NT=2, and per-CU B traffic halved vs the 64-position structure
// (B loads are per-wave; waves/CU halve at M=128).
template<int NT>
__device__ __forceinline__ void dist_pass(int p7b,
                                          const u16* __restrict__ pk,
                                          const u16* __restrict__ fwin,
                                          const float* __restrict__ sarr,
                                          const float* __restrict__ p2g,
                                          u32* __restrict__ wsm,
                                          int b, int wv, int lane) {
    const int m    = lane & 31;
    const int half = lane >> 5;
    const int koff = half * 8;

    f32x16 acc[NT][4];
    #pragma unroll
    for (int n = 0; n < NT; ++n)
        #pragma unroll
        for (int g = 0; g < 4; ++g)
            #pragma unroll
            for (int i = 0; i < 16; ++i) acc[n][g][i] = 0.f;

    const u16* pkl = pk + (size_t)lane * 8;

    #pragma unroll 2
    for (int tap = 0; tap < 16; ++tap) {
        #pragma unroll
        for (int cs = 0; cs < 4; ++cs) {
            const int co = cs * 16 + koff;
            FragU a[4];
            const u16* ap = &fwin[(wv * 128 + m + tap) * FST + co];
            #pragma unroll
            for (int g = 0; g < 4; ++g) {
                const u16* aq = ap + g * (32 * FST);
                a[g].u2[0] = *(const uint2*)aq;
                a[g].u2[1] = *(const uint2*)(aq + 4);
            }
            #pragma unroll
            for (int n = 0; n < NT; ++n) {
                FragU bF;
                bF.v = *(const s16x8*)(pkl +
                        (size_t)(((p7b + n) * 16 + tap) * 4 + cs) * 512);
                #pragma unroll
                for (int g = 0; g < 4; ++g)
                    acc[n][g] = __builtin_amdgcn_mfma_f32_32x32x16_bf16(a[g].v, bF.v, acc[n][g], 0, 0, 0);
            }
        }
    }

    // epilogue: d = s[pos] - 2*xp + p2[proto]; min over this wave's 128 positions
    // C layout (verified m74/m101): col = lane&31, row = (reg&3) + 8*(reg>>2) + 4*(lane>>5)
    #pragma unroll
    for (int n = 0; n < NT; ++n) {
        const int p7 = p7b + n;
        const float p2v = p2g[p7 * 32 + m];
        float dmin = 3.4e38f;
        #pragma unroll
        for (int g = 0; g < 4; ++g)
            #pragma unroll
            for (int reg = 0; reg < 16; ++reg) {
                const int row = g * 32 + (reg & 3) + 8 * (reg >> 2) + 4 * half;
                dmin = fminf(dmin, sarr[wv * 128 + row] - 2.f * acc[n][g][reg] + p2v);
            }
        dmin = fminf(dmin, __shfl_xor(dmin, 32));   // merge the two half-wave row sets
        if (half == 0 && p7 * 32 + m < PN)
            atomicMin(&wsm[b * PN + p7 * 32 + m], (u32)__float_as_uint(fmaxf(dmin, 0.f)));
    }
}

// K1: block = (chunk of 512 positions, batch); grid 16x32 = 512 blocks = exactly
// 2 blocks/CU resident (8 waves/CU: intentional occupancy-for-B-dedup trade).
// Phase 1: MFMA encoder (17 m-tiles of 32 rows; wave w owns tiles w, w+4, ...).
// Phase 2: g = ||f2||^2 then sliding 16-sum (gwin in place).
// Phase 3: distance GEMM, wave-M = 128, proto passes 2+2+2+1.
// Tail: last block per batch (atomic counter) computes the head in-kernel
//   (wsm read via identity atomicMin -> device-scope coherent across XCDs).
__global__ void __launch_bounds__(256, 2) k_dist(const u16* __restrict__ xT,
                                                 const u16* __restrict__ wpk,
                                                 const u16* __restrict__ pk,
                                                 u32* __restrict__ wsm,
                                                 u32* __restrict__ cnt,
                                                 const float* __restrict__ p2g,
                                                 const float* __restrict__ lw,
                                                 float* __restrict__ out) {
    __shared__ __align__(16) u16 fwin[WIN * FST];    // 71808 B, [slot][ch] bf16
    __shared__ float gwin[WIN];                      // 2112 B; g then s
    __shared__ u32 lastf;                            // (total 73924 B -> 2 blk/CU)

    const int t  = threadIdx.x;
    const int ck = blockIdx.x;           // 0..15
    const int b  = blockIdx.y;           // 0..31
    const int base = ck * CHK;

    const int lane = t & 63;
    const int wv   = t >> 6;
    const int m    = lane & 31;
    const int half = lane >> 5;
    const int koff = half * 8;

    const u16* wpkl = wpk + (size_t)lane * 8;
    const u16* xTb  = xT + (size_t)b * XSLOT * 16;

    // ---------------- Phase 1: MFMA encoder (17 tiles) ----------------
    #pragma unroll 1
    for (int mt = wv; mt < 17; mt += 4) {
        const int ar = mt * 32 + m;                  // this lane's A row
        // GEMM1: f1 = relu(conv3(x)), tap-decomposed, K=16 ci per tap
        f32x16 c1[2];
        #pragma unroll
        for (int i = 0; i < 16; ++i) { c1[0][i] = 0.f; c1[1][i] = 0.f; }
        #pragma unroll
        for (int tau = 0; tau < 3; ++tau) {
            FragU aF;
            aF.v = *(const s16x8*)(xTb + (size_t)(base + ar + tau) * 16 + koff);
            #pragma unroll
            for (int nt = 0; nt < 2; ++nt) {
                FragU bW; bW.v = *(const s16x8*)(wpkl + (size_t)(tau * 2 + nt) * 512);
                c1[nt] = __builtin_amdgcn_mfma_f32_32x32x16_bf16(aF.v, bW.v, c1[nt], 0, 0, 0);
            }
        }
        #pragma unroll
        for (int nt = 0; nt < 2; ++nt) {
            const int col = nt * 32 + m;
            #pragma unroll
            for (int reg = 0; reg < 16; ++reg) {
                const int row = mt * 32 + (reg & 3) + 8 * (reg >> 2) + 4 * half;
                if (row < WIN) fwin[row * FST + col] = vf2b(fmaxf(c1[nt][reg], 0.f));
            }
        }
        // GEMM2: f2 = relu(wa . f1), K=64 in 4 cs slices; reads then overwrites same rows
        f32x16 c2[2];
        #pragma unroll
        for (int i = 0; i < 16; ++i) { c2[0][i] = 0.f; c2[1][i] = 0.f; }
        FragU a2[4];
        const int arc = (ar < WIN) ? ar : (WIN - 1);   // clamp tile-16 dead rows (row 527 in tile)
        #pragma unroll
        for (int cs = 0; cs < 4; ++cs) {
            const u16* ap = &fwin[arc * FST + cs * 16 + koff];
            a2[cs].u2[0] = *(const uint2*)ap;
            a2[cs].u2[1] = *(const uint2*)(ap + 4);
        }
        #pragma unroll
        for (int cs = 0; cs < 4; ++cs)
            #pragma unroll
            for (int nt = 0; nt < 2; ++nt) {
                FragU bW; bW.v = *(const s16x8*)(wpkl + (size_t)(6 + cs * 2 + nt) * 512);
                c2[nt] = __builtin_amdgcn_mfma_f32_32x32x16_bf16(a2[cs].v, bW.v, c2[nt], 0, 0, 0);
            }
        #pragma unroll
        for (int nt = 0; nt < 2; ++nt) {
            const int col = nt * 32 + m;
            #pragma unroll
            for (int reg = 0; reg < 16; ++reg) {
                const int row = mt * 32 + (reg & 3) + 8 * (reg >> 2) + 4 * half;
                if (row < WIN) fwin[row * FST + col] = vf2b(fmaxf(c2[nt][reg], 0.f));
            }
        }
    }
    __syncthreads();

    // ---------------- Phase 2a: per-slot g = ||f2||^2 (528 rows / 256 threads) ----
    {
        float gs[3] = {0.f, 0.f, 0.f};
        #pragma unroll
        for (int rr = 0; rr < 3; ++rr) {
            const int row = rr * 256 + t;
            if (row < WIN) {
                const uint2* r0 = (const uint2*)(fwin + (size_t)row * FST);
                float s = 0.f;
                #pragma unroll
                for (int i = 0; i < 16; ++i) {
                    uint2 v = r0[i];
                    float a = __uint_as_float(v.x << 16);
                    float bb = __uint_as_float(v.x & 0xffff0000u);
                    float c = __uint_as_float(v.y << 16);
                    float d = __uint_as_float(v.y & 0xffff0000u);
                    s += a * a + bb * bb + c * c + d * d;
                }
                gs[rr] = s;
            }
        }
        gwin[t] = gs[0];
        gwin[256 + t] = gs[1];
        if (t < 16) gwin[512 + t] = gs[2];
    }
    __syncthreads();

    // ---------------- Phase 2b: sliding patch-norm (poison tail), overwrite gwin ----
    {
        float sv0 = 0.f, sv1 = 0.f;
        #pragma unroll
        for (int k = 0; k < PLEN; ++k) sv0 += gwin[t + k];
        #pragma unroll
        for (int k = 0; k < PLEN; ++k) sv1 += gwin[256 + t + k];
        sv0 = (base + t < LOV)       ? sv0 : 3.0e38f;
        sv1 = (base + 256 + t < LOV) ? sv1 : 3.0e38f;
        __syncthreads();
        gwin[t] = sv0;
        gwin[256 + t] = sv1;
    }
    __syncthreads();

    // ---------------- Phase 3: distance GEMM ----------------
    dist_pass<2>(0, pk, fwin, gwin, p2g, wsm, b, wv, lane);
    dist_pass<2>(2, pk, fwin, gwin, p2g, wsm, b, wv, lane);
    dist_pass<2>(4, pk, fwin, gwin, p2g, wsm, b, wv, lane);
    dist_pass<1>(6, pk, fwin, gwin, p2g, wsm, b, wv, lane);

    // ---------------- Tail: last block of this batch computes the head ----------------
    __threadfence();                       // order my atomicMins before the counter bump
    if (t == 0) lastf = (atomicAdd(&cnt[b], 1) == 15) ? 1u : 0u;
    __syncthreads();
    if (lastf) {
        if (t < PN) {
            // identity atomicMin = device-scope coherent read of the global min
            u32 bits = atomicMin(&wsm[b * PN + t], 0x7f7fffffu);
            float md = __uint_as_float(bits);
            md = fminf(fmaxf(md, 0.f), 2000.f);
            if (!(md == md)) md = 0.f;
            out[MD0 + b * PN + t] = md;
            gwin[t] = logf((md + 1.f) / (md + EPSV));
        }
        __syncthreads();
        if (t < NCLS) {
            float sum = 0.f;
            #pragma unroll 1
            for (int p = 0; p < PN; ++p) sum += gwin[p] * lw[t * PN + p];
            sum = fminf(fmaxf(sum, -100.f), 100.f);
            if (!(sum == sum)) sum = 0.f;
            out[b * NCLS + t] = sum;
        }
    }
}

extern "C" void kernel_launch(void* const* d_in, const int* in_sizes, int n_in,
                              void* d_out, int out_size, void* d_ws, size_t ws_size,
                              hipStream_t stream) {
    // Inputs are FLOAT32. Resolve by unique element count (order-proof).
    const float* x  = 0;   // 32*16*8192 = 4194304
    const float* we = 0;   // 64*16*3    = 3072
    const float* wa = 0;   // 64*64*1    = 4096
    const float* pt = 0;   // 200*64*16  = 204800
    const float* lw = 0;   // 10*200     = 2000
    for (int i = 0; i < n_in; ++i) {
        switch (in_sizes[i]) {
            case 4194304: x  = (const float*)d_in[i]; break;
            case 3072:    we = (const float*)d_in[i]; break;
            case 4096:    wa = (const float*)d_in[i]; break;
            case 204800:  pt = (const float*)d_in[i]; break;
            case 2000:    lw = (const float*)d_in[i]; break;
            default: break;
        }
    }
    if (!x || !we || !wa || !pt || !lw) {
        x  = (const float*)d_in[0];
        we = (const float*)d_in[1];
        wa = (const float*)d_in[2];
        pt = (const float*)d_in[3];
        lw = (const float*)d_in[4];
    }
    float* out = (float*)d_out;   // f32: [0:320) logits, [320:6720) min_distances

    // Workspace layout (all 16B-aligned):
    char* ws  = (char*)d_ws;
    u32*   wsm = (u32*)ws;                 // 25600 B
    float* p2g = (float*)(ws + 25600);     // 896 B   -> 26496
    u32*   cnt = (u32*)(ws + 26496);       // 128 B   -> 26624
    u16*   pk  = (u16*)(ws + 26624);       // 917504  -> 944128
    u16*   wpk = (u16*)(ws + 944128);      // 14336   -> 958464
    u16*   xT  = (u16*)(ws + 958464);      // 8454144 -> 9412608 (~9.0 MB total)

    k_prep<<<dim3(NTRB + 64), dim3(256), 0, stream>>>(x, we, wa, pt, wsm, cnt, p2g, pk, wpk, xT);
    k_dist<<<dim3(16, 32), dim3(256), 0, stream>>>(xT, wpk, pk, wsm, cnt, p2g, lw, out);
}